// Round 1
// 2191.646 us; speedup vs baseline: 1.2175x; 1.2175x over previous
//
#include <hip/hip_runtime.h>

#define Hn 1024
#define Bn 8
#define Ln 4096
#define DIn 2048
#define NCH 64
#define CLn 64   // Ln / NCH

typedef __attribute__((ext_vector_type(8))) short short8;
typedef __attribute__((ext_vector_type(4))) short short4v;
typedef __attribute__((ext_vector_type(4))) float f32x4;

__device__ __forceinline__ float bf2f(short s) {
  return __uint_as_float(((unsigned)(unsigned short)s) << 16);
}
__device__ __forceinline__ short f2bf(float f) {
  unsigned u = __float_as_uint(f);
  u += 0x7fffu + ((u >> 16) & 1u);
  return (short)(u >> 16);
}
__device__ __forceinline__ float silu_f(float x) { return x / (1.f + __expf(-x)); }
__device__ __forceinline__ float softplus_f(float x) { return x > 20.f ? x : log1pf(__expf(x)); }

__device__ __forceinline__ void gld16(const short* g, short* l) {
  __builtin_amdgcn_global_load_lds((const __attribute__((address_space(1))) void*)g,
                                   (__attribute__((address_space(3))) void*)l, 16, 0, 0);
}

// ---------------- fp32 -> bf16 convert (x4 vectorized) ----------------
__global__ __launch_bounds__(256) void f2bf4_kernel(const float* __restrict__ in,
                                                    short* __restrict__ out, int n4) {
  int i = blockIdx.x * 256 + threadIdx.x;
  if (i < n4) {
    f32x4 v = ((const f32x4*)in)[i];
    short4v o;
    o.x = f2bf(v.x); o.y = f2bf(v.y); o.z = f2bf(v.z); o.w = f2bf(v.w);
    ((short4v*)out)[i] = o;
  }
}

// ---------------- adaLN modulation ----------------
__global__ __launch_bounds__(256) void modcalc_kernel(const float* __restrict__ c,
    const float* __restrict__ aw, const float* __restrict__ ab, float* __restrict__ mod) {
  int wid = blockIdx.x * 4 + (threadIdx.x >> 6);
  int lane = threadIdx.x & 63;
  int b = wid / 3072, n = wid - b * 3072;
  const f32x4* cr = (const f32x4*)(c + b * Hn);
  const f32x4* wr = (const f32x4*)(aw + (size_t)n * Hn);
  float s = 0.f;
#pragma unroll
  for (int i = 0; i < 4; ++i) {
    f32x4 cv = cr[lane + 64 * i];
    f32x4 wv = wr[lane + 64 * i];
    s += silu_f(cv.x) * wv.x + silu_f(cv.y) * wv.y + silu_f(cv.z) * wv.z + silu_f(cv.w) * wv.w;
  }
#pragma unroll
  for (int m = 1; m < 64; m <<= 1) s += __shfl_xor(s, m, 64);
  if (lane == 0) mod[wid] = s + ab[n];
}

// ---------------- LayerNorm + modulate -> x1 (bf16) ----------------
__global__ __launch_bounds__(256) void ln_mod_kernel(const float* __restrict__ x,
    const float* __restrict__ mod, short* __restrict__ x1, int b0) {
  int row = blockIdx.x * 4 + (threadIdx.x >> 6);
  int lane = threadIdx.x & 63;
  int b = b0 + (row >> 12);
  const f32x4* xr = (const f32x4*)(x + (size_t)row * Hn);
  f32x4 v[4];
  float s = 0.f, ss = 0.f;
#pragma unroll
  for (int i = 0; i < 4; ++i) {
    v[i] = xr[lane + 64 * i];
    s += v[i].x + v[i].y + v[i].z + v[i].w;
    ss += v[i].x * v[i].x + v[i].y * v[i].y + v[i].z * v[i].z + v[i].w * v[i].w;
  }
#pragma unroll
  for (int m = 1; m < 64; m <<= 1) {
    s += __shfl_xor(s, m, 64);
    ss += __shfl_xor(ss, m, 64);
  }
  float mu = s * (1.f / 1024.f);
  float var = ss * (1.f / 1024.f) - mu * mu;
  float r = rsqrtf(var + 1e-6f);
  const f32x4* shp = (const f32x4*)(mod + b * 3072);
  const f32x4* scp = (const f32x4*)(mod + b * 3072 + 1024);
#pragma unroll
  for (int i = 0; i < 4; ++i) {
    int k4 = lane + 64 * i;
    f32x4 sc = scp[k4], sh = shp[k4];
    short4v o;
    o.x = f2bf((v[i].x - mu) * r * (1.f + sc.x) + sh.x);
    o.y = f2bf((v[i].y - mu) * r * (1.f + sc.y) + sh.y);
    o.z = f2bf((v[i].z - mu) * r * (1.f + sc.z) + sh.z);
    o.w = f2bf((v[i].w - mu) * r * (1.f + sc.w) + sh.w);
    *(short4v*)&x1[(size_t)row * Hn + k4 * 4] = o;
  }
}

// ---------------- generic bf16 MFMA GEMM: out = A[M,K] @ W[N,K]^T (+epilogue) ----------------
// register-staged + padded LDS; used for edge shapes (N % 128 != 0 or small K)
#define SA_STR 40
template <int EPI>
__global__ __launch_bounds__(256) void gemm_k(
    const short* __restrict__ A, const short* __restrict__ W,
    const float* __restrict__ bias, const short* mul,
    const float* __restrict__ xres, const float* __restrict__ modp,
    void* outp, int N, int K, int b0) {
  __shared__ short sA[128 * SA_STR];
  __shared__ short sB[128 * SA_STR];
  int tid = threadIdx.x;
  int wave = tid >> 6, lane = tid & 63;
  int bm0 = blockIdx.y * 128;
  int bn0 = blockIdx.x * 128;
  int wm = (wave >> 1) * 64, wn = (wave & 1) * 64;
  int lrow = lane & 15, kh = (lane >> 4) * 8;
  int srow = tid >> 2;
  int scol = (tid & 3) * 8;

  f32x4 acc[4][4];
#pragma unroll
  for (int i = 0; i < 4; i++)
#pragma unroll
    for (int j = 0; j < 4; j++) acc[i][j] = (f32x4)0.f;

  for (int k0 = 0; k0 < K; k0 += 32) {
#pragma unroll
    for (int p = 0; p < 2; ++p) {
      int r = srow + p * 64;
      short8 av = *(const short8*)&A[(size_t)(bm0 + r) * K + k0 + scol];
      *(short8*)&sA[r * SA_STR + scol] = av;
      int n = bn0 + r;
      short8 bv = (short8)0;
      if (n < N) bv = *(const short8*)&W[(size_t)n * K + k0 + scol];
      *(short8*)&sB[r * SA_STR + scol] = bv;
    }
    __syncthreads();
    short8 af[4], bfr[4];
#pragma unroll
    for (int i = 0; i < 4; i++) af[i] = *(const short8*)&sA[(wm + i * 16 + lrow) * SA_STR + kh];
#pragma unroll
    for (int j = 0; j < 4; j++) bfr[j] = *(const short8*)&sB[(wn + j * 16 + lrow) * SA_STR + kh];
#pragma unroll
    for (int i = 0; i < 4; i++)
#pragma unroll
      for (int j = 0; j < 4; j++)
        acc[i][j] = __builtin_amdgcn_mfma_f32_16x16x32_bf16(af[i], bfr[j], acc[i][j], 0, 0, 0);
    __syncthreads();
  }

  int orow4 = (lane >> 4) * 4;
  int ocol = lane & 15;
#pragma unroll
  for (int i = 0; i < 4; i++)
#pragma unroll
    for (int j = 0; j < 4; j++)
#pragma unroll
      for (int r = 0; r < 4; r++) {
        int row = bm0 + wm + i * 16 + orow4 + r;
        int col = bn0 + wn + j * 16 + ocol;
        if (col >= N) continue;
        float v = acc[i][j][r];
        size_t idx = (size_t)row * N + col;
        if (EPI == 0) {
          ((short*)outp)[idx] = f2bf(v);
        } else if (EPI == 1) {
          ((short*)outp)[idx] = f2bf(v + bias[col]);
        } else if (EPI == 2) {
          ((short*)outp)[idx] = f2bf(silu_f(v + bias[col]));
        } else if (EPI == 3) {
          ((short*)outp)[idx] = f2bf(softplus_f(v + bias[col]));
        } else if (EPI == 4) {
          float t = silu_f(v + bias[col]) * bf2f(mul[idx]);
          ((short*)outp)[idx] = f2bf(t);
        } else if (EPI == 5) {
          ((float*)outp)[idx] = v;
        } else if (EPI == 6) {
          int b = b0 + (row >> 12);
          float t = v + bias[col];
          ((float*)outp)[idx] = xres[idx] + modp[b * 3072 + 2048 + col] * t;
        } else if (EPI == 7) {
          float t = silu_f(v) * bf2f(mul[idx]);
          ((short*)outp)[idx] = f2bf(t);
        }
      }
}

// ---------------- full-tile bf16 GEMM via global_load_lds (m97 structure) ----------------
// Requires M%128==0, N%128==0, K%32==0. EPI: 0 = plain bf16 store, 7 = silu(v)*mul store.
template <int EPI>
__global__ __launch_bounds__(256) void gemm_lds_k(
    const short* __restrict__ A, const short* __restrict__ W,
    const short* mul, void* outp, int N, int K) {
  __shared__ short sA[128 * 32];
  __shared__ short sB[128 * 32];
  int tid = threadIdx.x;
  int wave = tid >> 6, lane = tid & 63;
  int bm0 = blockIdx.y * 128;
  int bn0 = blockIdx.x * 128;
  int wm = (wave >> 1) * 64, wn = (wave & 1) * 64;
  int lrow = lane & 15, kh = (lane >> 4) * 8;
  int srow = tid >> 2;       // 0..63
  int scol = (tid & 3) * 8;  // shorts

  const short* Ab = A + (size_t)(bm0 + srow) * K + scol;
  const short* Bb = W + (size_t)(bn0 + srow) * K + scol;
  short* sAp = &sA[srow * 32 + scol];  // == wave_base + lane*16B (linear)
  short* sBp = &sB[srow * 32 + scol];

  f32x4 acc[4][4];
#pragma unroll
  for (int i = 0; i < 4; i++)
#pragma unroll
    for (int j = 0; j < 4; j++) acc[i][j] = (f32x4)0.f;

  for (int k0 = 0; k0 < K; k0 += 32) {
    gld16(Ab + k0, sAp);
    gld16(Ab + k0 + (size_t)64 * K, sAp + 64 * 32);
    gld16(Bb + k0, sBp);
    gld16(Bb + k0 + (size_t)64 * K, sBp + 64 * 32);
    __syncthreads();
    short8 af[4], bfr[4];
#pragma unroll
    for (int i = 0; i < 4; i++) af[i] = *(const short8*)&sA[(wm + i * 16 + lrow) * 32 + kh];
#pragma unroll
    for (int j = 0; j < 4; j++) bfr[j] = *(const short8*)&sB[(wn + j * 16 + lrow) * 32 + kh];
#pragma unroll
    for (int i = 0; i < 4; i++)
#pragma unroll
      for (int j = 0; j < 4; j++)
        acc[i][j] = __builtin_amdgcn_mfma_f32_16x16x32_bf16(af[i], bfr[j], acc[i][j], 0, 0, 0);
    __syncthreads();
  }

  int orow4 = (lane >> 4) * 4;
  int ocol = lane & 15;
#pragma unroll
  for (int i = 0; i < 4; i++)
#pragma unroll
    for (int j = 0; j < 4; j++)
#pragma unroll
      for (int r = 0; r < 4; r++) {
        int row = bm0 + wm + i * 16 + orow4 + r;
        int col = bn0 + wn + j * 16 + ocol;
        float v = acc[i][j][r];
        size_t idx = (size_t)row * N + col;
        if (EPI == 0) {
          ((short*)outp)[idx] = f2bf(v);
        } else if (EPI == 7) {
          float t = silu_f(v) * bf2f(mul[idx]);
          ((short*)outp)[idx] = f2bf(t);
        }
      }
}

// ---------------- causal depthwise conv (DC=4) + SiLU ----------------
__global__ __launch_bounds__(256) void conv_kernel(const short* __restrict__ xm,
    const float* __restrict__ cw, const float* __restrict__ cb, short* __restrict__ xc) {
  size_t idx = (size_t)blockIdx.x * 256 + threadIdx.x;
  int d = (int)(idx & (DIn - 1));
  size_t bt = idx >> 11;
  int t = (int)(bt & (Ln - 1));
  f32x4 w = *(const f32x4*)(cw + d * 4);
  float wj[4] = {w.x, w.y, w.z, w.w};
  float acc = cb[d];
#pragma unroll
  for (int j = 0; j < 4; ++j) {
    int tt = t - 3 + j;
    if (tt >= 0) acc += bf2f(xm[(bt - 3 + j) * DIn + d]) * wj[j];
  }
  xc[idx] = f2bf(silu_f(acc));
}

// ---------------- slice dbl[:, :64] -> bf16 ----------------
__global__ __launch_bounds__(256) void dtslice_kernel(const float* __restrict__ dbl,
                                                      short* __restrict__ dtb) {
  int idx = blockIdx.x * 256 + threadIdx.x;
  int row = idx >> 6, col = idx & 63;
  dtb[idx] = f2bf(dbl[(size_t)row * 96 + col]);
}

// ================= chunked parallel selective scan =================
// thread g -> d = g&2047, c = (g>>11)&63, b = g>>17 (within chunk-batch BC)
// pass 1: local scan from h=0 over CLn steps; store h_end[16] + sum(dt)
__global__ __launch_bounds__(256) void scan_part1(const short* __restrict__ dt,
    const short* __restrict__ xc, const float* __restrict__ dbl,
    const float* __restrict__ A_log, float* __restrict__ hq, float* __restrict__ sd) {
  __shared__ float sB[CLn * 16];
  int tid = threadIdx.x;
  int g = blockIdx.x * 256 + tid;
  int d = g & (DIn - 1);
  int r = g >> 11;
  int c = r & (NCH - 1);
  int b = r >> 6;
  size_t rb = (size_t)b * Ln + (size_t)c * CLn;
  // stage B rows (shared by whole block): 64 rows x 16 floats = 4 KB
  {
    int row = tid >> 2, q = tid & 3;
    *(f32x4*)&sB[row * 16 + q * 4] = *(const f32x4*)(dbl + (rb + row) * 96 + 64 + q * 4);
  }
  __syncthreads();
  float A[16], h[16];
#pragma unroll
  for (int s = 0; s < 16; ++s) {
    A[s] = -__expf(A_log[d * 16 + s]);
    h[s] = 0.f;
  }
  // structure check: A[s] == (s+1)*A[0] (Mamba arange init) -> one exp + powers
  bool st = true;
#pragma unroll
  for (int s = 1; s < 16; ++s)
    st = st && (fabsf(A[s] - (float)(s + 1) * A[0]) <= 1e-4f * fabsf(A[s]));
  float A0 = A[0];
  float sum = 0.f;
  const short* dp = dt + rb * DIn + d;
  const short* xp = xc + rb * DIn + d;
  short dtn = *dp, xcn = *xp;
  if (st) {
    for (int t = 0; t < CLn; ++t) {
      float dtv = bf2f(dtn), xv = bf2f(xcn);
      int tn = (t + 1 < CLn) ? t + 1 : t;
      dtn = dp[(size_t)tn * DIn];
      xcn = xp[(size_t)tn * DIn];
      float u = dtv * xv;
      sum += dtv;
      const f32x4* bp = (const f32x4*)&sB[t * 16];
      f32x4 b0 = bp[0], b1 = bp[1], b2 = bp[2], b3 = bp[3];
      float bv[16] = {b0.x, b0.y, b0.z, b0.w, b1.x, b1.y, b1.z, b1.w,
                      b2.x, b2.y, b2.z, b2.w, b3.x, b3.y, b3.z, b3.w};
      float qe = __expf(dtv * A0);
      float pk = qe;
#pragma unroll
      for (int s = 0; s < 16; ++s) {
        h[s] = h[s] * pk + u * bv[s];
        pk *= qe;
      }
    }
  } else {
    for (int t = 0; t < CLn; ++t) {
      float dtv = bf2f(dtn), xv = bf2f(xcn);
      int tn = (t + 1 < CLn) ? t + 1 : t;
      dtn = dp[(size_t)tn * DIn];
      xcn = xp[(size_t)tn * DIn];
      float u = dtv * xv;
      sum += dtv;
      const f32x4* bp = (const f32x4*)&sB[t * 16];
      f32x4 b0 = bp[0], b1 = bp[1], b2 = bp[2], b3 = bp[3];
      float bv[16] = {b0.x, b0.y, b0.z, b0.w, b1.x, b1.y, b1.z, b1.w,
                      b2.x, b2.y, b2.z, b2.w, b3.x, b3.y, b3.z, b3.w};
#pragma unroll
      for (int s = 0; s < 16; ++s) h[s] = h[s] * __expf(dtv * A[s]) + u * bv[s];
    }
  }
  size_t bd = (size_t)b * DIn + d;
  f32x4* out = (f32x4*)(hq + (bd * NCH + c) * 16);
#pragma unroll
  for (int i = 0; i < 4; ++i) {
    f32x4 o; o.x = h[4 * i]; o.y = h[4 * i + 1]; o.z = h[4 * i + 2]; o.w = h[4 * i + 3];
    out[i] = o;
  }
  sd[bd * NCH + c] = sum;
}

// pass combine: thread per (b,d,s); sequential over chunks; hq becomes h_start
__global__ __launch_bounds__(256) void scan_combine(const float* __restrict__ A_log,
    const float* __restrict__ sd, float* hq) {
  int g = blockIdx.x * 256 + threadIdx.x;
  int s = g & 15;
  size_t bd = (size_t)(g >> 4);
  int d = (int)(bd & (DIn - 1));
  float A = -__expf(A_log[d * 16 + s]);
  float H = 0.f;
  for (int c = 0; c < NCH; ++c) {
    size_t idx = (bd * NCH + c) * 16 + s;
    float he = hq[idx];
    float e = __expf(A * sd[bd * NCH + c]);
    hq[idx] = H;
    H = H * e + he;
  }
}

// pass 2: local scan seeded with h_start; y = h·C + xc*D. dt/y may alias (read-t-then-write-t).
__global__ __launch_bounds__(256) void scan_part2(const short* dt,
    const short* __restrict__ xc, const float* __restrict__ dbl,
    const float* __restrict__ A_log, const float* __restrict__ Dv,
    const float* __restrict__ hq, short* y) {
  __shared__ float sBC[CLn * 32];
  int tid = threadIdx.x;
  int g = blockIdx.x * 256 + tid;
  int d = g & (DIn - 1);
  int r = g >> 11;
  int c = r & (NCH - 1);
  int b = r >> 6;
  size_t rb = (size_t)b * Ln + (size_t)c * CLn;
  // stage B+C rows (shared by whole block): 64 rows x 32 floats = 8 KB
  {
    int row = tid >> 2, q = tid & 3;
    const float* src = dbl + (rb + row) * 96 + 64 + q * 8;
    *(f32x4*)&sBC[row * 32 + q * 8] = *(const f32x4*)src;
    *(f32x4*)&sBC[row * 32 + q * 8 + 4] = *(const f32x4*)(src + 4);
  }
  __syncthreads();
  size_t bd = (size_t)b * DIn + d;
  float A[16], h[16];
#pragma unroll
  for (int s = 0; s < 16; ++s) A[s] = -__expf(A_log[d * 16 + s]);
  const f32x4* hin = (const f32x4*)(hq + (bd * NCH + c) * 16);
#pragma unroll
  for (int i = 0; i < 4; ++i) {
    f32x4 qv = hin[i];
    h[4 * i] = qv.x; h[4 * i + 1] = qv.y; h[4 * i + 2] = qv.z; h[4 * i + 3] = qv.w;
  }
  bool st = true;
#pragma unroll
  for (int s = 1; s < 16; ++s)
    st = st && (fabsf(A[s] - (float)(s + 1) * A[0]) <= 1e-4f * fabsf(A[s]));
  float A0 = A[0];
  float Dd = Dv[d];
  const short* dp = dt + rb * DIn + d;
  const short* xp = xc + rb * DIn + d;
  short* yp = y + rb * DIn + d;
  short dtn = *dp, xcn = *xp;
  if (st) {
    for (int t = 0; t < CLn; ++t) {
      float dtv = bf2f(dtn), xv = bf2f(xcn);
      int tn = (t + 1 < CLn) ? t + 1 : t;
      dtn = dp[(size_t)tn * DIn];   // prefetch before y-store (alias-safe: different row)
      xcn = xp[(size_t)tn * DIn];
      float u = dtv * xv;
      const f32x4* pp = (const f32x4*)&sBC[t * 32];
      f32x4 v0 = pp[0], v1 = pp[1], v2 = pp[2], v3 = pp[3];
      f32x4 v4 = pp[4], v5 = pp[5], v6 = pp[6], v7 = pp[7];
      float bc[32] = {v0.x, v0.y, v0.z, v0.w, v1.x, v1.y, v1.z, v1.w,
                      v2.x, v2.y, v2.z, v2.w, v3.x, v3.y, v3.z, v3.w,
                      v4.x, v4.y, v4.z, v4.w, v5.x, v5.y, v5.z, v5.w,
                      v6.x, v6.y, v6.z, v6.w, v7.x, v7.y, v7.z, v7.w};
      float qe = __expf(dtv * A0);
      float pk = qe, acc = 0.f;
#pragma unroll
      for (int s = 0; s < 16; ++s) {
        h[s] = h[s] * pk + u * bc[s];
        acc += h[s] * bc[16 + s];
        pk *= qe;
      }
      yp[(size_t)t * DIn] = f2bf(acc + xv * Dd);
    }
  } else {
    for (int t = 0; t < CLn; ++t) {
      float dtv = bf2f(dtn), xv = bf2f(xcn);
      int tn = (t + 1 < CLn) ? t + 1 : t;
      dtn = dp[(size_t)tn * DIn];
      xcn = xp[(size_t)tn * DIn];
      float u = dtv * xv;
      const f32x4* pp = (const f32x4*)&sBC[t * 32];
      f32x4 v0 = pp[0], v1 = pp[1], v2 = pp[2], v3 = pp[3];
      f32x4 v4 = pp[4], v5 = pp[5], v6 = pp[6], v7 = pp[7];
      float bc[32] = {v0.x, v0.y, v0.z, v0.w, v1.x, v1.y, v1.z, v1.w,
                      v2.x, v2.y, v2.z, v2.w, v3.x, v3.y, v3.z, v3.w,
                      v4.x, v4.y, v4.z, v4.w, v5.x, v5.y, v5.z, v5.w,
                      v6.x, v6.y, v6.z, v6.w, v7.x, v7.y, v7.z, v7.w};
      float acc = 0.f;
#pragma unroll
      for (int s = 0; s < 16; ++s) {
        h[s] = h[s] * __expf(dtv * A[s]) + u * bc[s];
        acc += h[s] * bc[16 + s];
      }
      yp[(size_t)t * DIn] = f2bf(acc + xv * Dd);
    }
  }
}

extern "C" void kernel_launch(void* const* d_in, const int* in_sizes, int n_in,
                              void* d_out, int out_size, void* d_ws, size_t ws_size,
                              hipStream_t stream) {
  const float* x = (const float*)d_in[0];
  const float* c = (const float*)d_in[1];
  const float* adaln_w = (const float*)d_in[2];
  const float* adaln_b = (const float*)d_in[3];
  const float* hgd_w1 = (const float*)d_in[4];
  const float* hgd_b1 = (const float*)d_in[5];
  const float* hgd_w2 = (const float*)d_in[6];
  const float* hgd_b2 = (const float*)d_in[7];
  const float* hgf_wm = (const float*)d_in[8];
  const float* hgf_bm = (const float*)d_in[9];
  const float* hgf_wr = (const float*)d_in[10];
  const float* hgf_br = (const float*)d_in[11];
  const float* hgf_wf = (const float*)d_in[12];
  const float* hgf_bf = (const float*)d_in[13];
  const float* in_w = (const float*)d_in[14];
  const float* conv_w = (const float*)d_in[15];
  const float* conv_b = (const float*)d_in[16];
  const float* xproj_w = (const float*)d_in[17];
  const float* dtproj_w = (const float*)d_in[18];
  const float* dt_bias = (const float*)d_in[19];
  const float* A_log = (const float*)d_in[20];
  const float* Dv = (const float*)d_in[21];
  const float* out_w = (const float*)d_in[22];
  (void)in_sizes; (void)n_in; (void)out_size;

  // ---- persistent region: bf16 weights + modulation ----
  char* ws = (char*)d_ws;
  size_t off = 0;
  auto alloc = [&](size_t bytes) -> void* {
    void* p = ws + off;
    off += (bytes + 255) & ~(size_t)255;
    return p;
  };
  short* w1b = (short*)alloc((size_t)256 * 1024 * 2);
  short* w2b = (short*)alloc((size_t)1024 * 256 * 2);
  short* wmb = (short*)alloc((size_t)256 * 1024 * 2);
  short* wrb = (short*)alloc((size_t)256 * 1024 * 2);
  short* wfb = (short*)alloc((size_t)1024 * 256 * 2);
  short* inwb = (short*)alloc((size_t)4096 * 1024 * 2);
  short* xpb = (short*)alloc((size_t)96 * 2048 * 2);
  short* dtpb = (short*)alloc((size_t)2048 * 64 * 2);
  short* owb = (short*)alloc((size_t)1024 * 2048 * 2);
  float* modb = (float*)alloc((size_t)Bn * 3072 * 4);
  size_t persist = off;

  // ---- batch-chunking: per-chunk bytes = Mc*14976 (incl. hq/sd) ----
  int BC = 8;
  while (BC > 1 && persist + (size_t)BC * Ln * 14976 > ws_size) BC >>= 1;
  int nchunk = 8 / BC;
  size_t Mc = (size_t)BC * Ln;

  short* x1 = (short*)alloc(Mc * 1024 * 2);
  short* hd = (short*)alloc(Mc * 1024 * 2);
  short* xm = (short*)alloc(Mc * 2048 * 2);   // in_proj x -> dt -> y_raw -> y
  short* xct = (short*)alloc(Mc * 2048 * 2);  // conv out; t1 aliases
  float* dbl = (float*)alloc(Mc * 96 * 4);
  short* dtb = (short*)alloc(Mc * 64 * 2);
  float* hq = (float*)alloc((size_t)BC * DIn * NCH * 16 * 4);
  float* sd = (float*)alloc((size_t)BC * DIn * NCH * 4);
  short* t1 = xct;

  auto conv1 = [&](const float* src, short* dst, int n) {
    f2bf4_kernel<<<(n / 4 + 255) / 256, 256, 0, stream>>>(src, dst, n / 4);
  };
  conv1(hgd_w1, w1b, 256 * 1024);
  conv1(hgd_w2, w2b, 1024 * 256);
  conv1(hgf_wm, wmb, 256 * 1024);
  conv1(hgf_wr, wrb, 256 * 1024);
  conv1(hgf_wf, wfb, 1024 * 256);
  conv1(in_w, inwb, 4096 * 1024);
  conv1(xproj_w, xpb, 96 * 2048);
  conv1(dtproj_w, dtpb, 2048 * 64);
  conv1(out_w, owb, 1024 * 2048);

  modcalc_kernel<<<(Bn * 3072) / 4, 256, 0, stream>>>(c, adaln_w, adaln_b, modb);

  dim3 blk(256);
  int gy = (int)(Mc / 128);
  for (int ck = 0; ck < nchunk; ++ck) {
    int b0 = ck * BC;
    const float* xch = x + (size_t)b0 * Ln * Hn;
    float* och = (float*)d_out + (size_t)b0 * Ln * Hn;

    ln_mod_kernel<<<(int)(Mc / 4), blk, 0, stream>>>(xch, modb, x1, b0);
    gemm_k<2><<<dim3(2, gy), blk, 0, stream>>>(x1, w1b, hgd_b1, nullptr, nullptr, nullptr, t1, 256, 1024, 0);
    gemm_k<1><<<dim3(8, gy), blk, 0, stream>>>(t1, w2b, hgd_b2, nullptr, nullptr, nullptr, hd, 1024, 256, 0);
    gemm_lds_k<0><<<dim3(16, gy), blk, 0, stream>>>(hd, inwb, nullptr, xm, 2048, 1024);
    conv_kernel<<<(int)(Mc * 2048 / 256), blk, 0, stream>>>(xm, conv_w, conv_b, xct);
    gemm_k<5><<<dim3(1, gy), blk, 0, stream>>>(xct, xpb, nullptr, nullptr, nullptr, nullptr, dbl, 96, 2048, 0);
    dtslice_kernel<<<(int)(Mc * 64 / 256), blk, 0, stream>>>(dbl, dtb);
    gemm_k<3><<<dim3(16, gy), blk, 0, stream>>>(dtb, dtpb, dt_bias, nullptr, nullptr, nullptr, xm, 2048, 64, 0);
    // chunked parallel scan: dt(xm), xc(xct), B/C(dbl) -> y_raw in place in xm
    scan_part1<<<(int)(BC * 512), blk, 0, stream>>>(xm, xct, dbl, A_log, hq, sd);
    scan_combine<<<(int)(BC * 128), blk, 0, stream>>>(A_log, sd, hq);
    scan_part2<<<(int)(BC * 512), blk, 0, stream>>>(xm, xct, dbl, A_log, Dv, hq, xm);
    // gating: y = silu(hd @ Wz^T) * y_raw (in place)
    gemm_lds_k<7><<<dim3(16, gy), blk, 0, stream>>>(hd, inwb + (size_t)2048 * 1024, xm, xm, 2048, 1024);
    gemm_lds_k<0><<<dim3(8, gy), blk, 0, stream>>>(xm, owb, nullptr, hd, 1024, 2048);
    gemm_k<2><<<dim3(2, gy), blk, 0, stream>>>(hd, wmb, hgf_bm, nullptr, nullptr, nullptr, t1, 256, 1024, 0);
    gemm_k<4><<<dim3(2, gy), blk, 0, stream>>>(x1, wrb, hgf_br, t1, nullptr, nullptr, t1, 256, 1024, 0);
    gemm_k<6><<<dim3(8, gy), blk, 0, stream>>>(t1, wfb, hgf_bf, nullptr, xch, modb, och, 1024, 256, b0);
  }
}

// Round 2
// 2033.375 us; speedup vs baseline: 1.3123x; 1.0778x over previous
//
#include <hip/hip_runtime.h>

#define Hn 1024
#define Bn 8
#define Ln 4096
#define DIn 2048
#define NCH 64
#define CLn 64   // Ln / NCH

typedef __attribute__((ext_vector_type(8))) short short8;
typedef __attribute__((ext_vector_type(4))) short short4v;
typedef __attribute__((ext_vector_type(4))) float f32x4;

__device__ __forceinline__ float bf2f(short s) {
  return __uint_as_float(((unsigned)(unsigned short)s) << 16);
}
__device__ __forceinline__ short f2bf(float f) {
  unsigned u = __float_as_uint(f);
  u += 0x7fffu + ((u >> 16) & 1u);
  return (short)(u >> 16);
}
__device__ __forceinline__ float silu_f(float x) { return x / (1.f + __expf(-x)); }
__device__ __forceinline__ float softplus_f(float x) { return x > 20.f ? x : log1pf(__expf(x)); }

__device__ __forceinline__ void gld16(const short* g, short* l) {
  __builtin_amdgcn_global_load_lds((const __attribute__((address_space(1))) void*)g,
                                   (__attribute__((address_space(3))) void*)l, 16, 0, 0);
}

// ---------------- fp32 -> bf16 convert (x4 vectorized) ----------------
__global__ __launch_bounds__(256) void f2bf4_kernel(const float* __restrict__ in,
                                                    short* __restrict__ out, int n4) {
  int i = blockIdx.x * 256 + threadIdx.x;
  if (i < n4) {
    f32x4 v = ((const f32x4*)in)[i];
    short4v o;
    o.x = f2bf(v.x); o.y = f2bf(v.y); o.z = f2bf(v.z); o.w = f2bf(v.w);
    ((short4v*)out)[i] = o;
  }
}

// ---------------- adaLN modulation ----------------
__global__ __launch_bounds__(256) void modcalc_kernel(const float* __restrict__ c,
    const float* __restrict__ aw, const float* __restrict__ ab, float* __restrict__ mod) {
  int wid = blockIdx.x * 4 + (threadIdx.x >> 6);
  int lane = threadIdx.x & 63;
  int b = wid / 3072, n = wid - b * 3072;
  const f32x4* cr = (const f32x4*)(c + b * Hn);
  const f32x4* wr = (const f32x4*)(aw + (size_t)n * Hn);
  float s = 0.f;
#pragma unroll
  for (int i = 0; i < 4; ++i) {
    f32x4 cv = cr[lane + 64 * i];
    f32x4 wv = wr[lane + 64 * i];
    s += silu_f(cv.x) * wv.x + silu_f(cv.y) * wv.y + silu_f(cv.z) * wv.z + silu_f(cv.w) * wv.w;
  }
#pragma unroll
  for (int m = 1; m < 64; m <<= 1) s += __shfl_xor(s, m, 64);
  if (lane == 0) mod[wid] = s + ab[n];
}

// ---------------- LayerNorm + modulate -> x1 (bf16) ----------------
__global__ __launch_bounds__(256) void ln_mod_kernel(const float* __restrict__ x,
    const float* __restrict__ mod, short* __restrict__ x1, int b0) {
  int row = blockIdx.x * 4 + (threadIdx.x >> 6);
  int lane = threadIdx.x & 63;
  int b = b0 + (row >> 12);
  const f32x4* xr = (const f32x4*)(x + (size_t)row * Hn);
  f32x4 v[4];
  float s = 0.f, ss = 0.f;
#pragma unroll
  for (int i = 0; i < 4; ++i) {
    v[i] = xr[lane + 64 * i];
    s += v[i].x + v[i].y + v[i].z + v[i].w;
    ss += v[i].x * v[i].x + v[i].y * v[i].y + v[i].z * v[i].z + v[i].w * v[i].w;
  }
#pragma unroll
  for (int m = 1; m < 64; m <<= 1) {
    s += __shfl_xor(s, m, 64);
    ss += __shfl_xor(ss, m, 64);
  }
  float mu = s * (1.f / 1024.f);
  float var = ss * (1.f / 1024.f) - mu * mu;
  float r = rsqrtf(var + 1e-6f);
  const f32x4* shp = (const f32x4*)(mod + b * 3072);
  const f32x4* scp = (const f32x4*)(mod + b * 3072 + 1024);
#pragma unroll
  for (int i = 0; i < 4; ++i) {
    int k4 = lane + 64 * i;
    f32x4 sc = scp[k4], sh = shp[k4];
    short4v o;
    o.x = f2bf((v[i].x - mu) * r * (1.f + sc.x) + sh.x);
    o.y = f2bf((v[i].y - mu) * r * (1.f + sc.y) + sh.y);
    o.z = f2bf((v[i].z - mu) * r * (1.f + sc.z) + sh.z);
    o.w = f2bf((v[i].w - mu) * r * (1.f + sc.w) + sh.w);
    *(short4v*)&x1[(size_t)row * Hn + k4 * 4] = o;
  }
}

// ---------------- generic bf16 MFMA GEMM: out = A[M,K] @ W[N,K]^T (+epilogue) ----------------
// register-staged + padded LDS, 2-phase double-buffered (T3 minimum recipe + T14 ordering).
// used for edge shapes (N % 128 != 0 or small K)
#define SA_STR 40
template <int EPI>
__global__ __launch_bounds__(256) void gemm_k(
    const short* __restrict__ A, const short* __restrict__ W,
    const float* __restrict__ bias, const short* mul,
    const float* __restrict__ xres, const float* __restrict__ modp,
    void* outp, int N, int K, int b0) {
  __shared__ short sA[2][128 * SA_STR];
  __shared__ short sB[2][128 * SA_STR];
  int tid = threadIdx.x;
  int wave = tid >> 6, lane = tid & 63;
  int bm0 = blockIdx.y * 128;
  int bn0 = blockIdx.x * 128;
  int wm = (wave >> 1) * 64, wn = (wave & 1) * 64;
  int lrow = lane & 15, kh = (lane >> 4) * 8;
  int srow = tid >> 2;
  int scol = (tid & 3) * 8;

  f32x4 acc[4][4];
#pragma unroll
  for (int i = 0; i < 4; i++)
#pragma unroll
    for (int j = 0; j < 4; j++) acc[i][j] = (f32x4)0.f;

  // prologue: stage k0=0 into buffer 0
#pragma unroll
  for (int p = 0; p < 2; ++p) {
    int r = srow + p * 64;
    short8 av = *(const short8*)&A[(size_t)(bm0 + r) * K + scol];
    *(short8*)&sA[0][r * SA_STR + scol] = av;
    int n = bn0 + r;
    short8 bv = (short8)0;
    if (n < N) bv = *(const short8*)&W[(size_t)n * K + scol];
    *(short8*)&sB[0][r * SA_STR + scol] = bv;
  }
  __syncthreads();

  int cur = 0;
  for (int k0 = 0; k0 < K; k0 += 32) {
    bool have = (k0 + 32) < K;
    // issue next-tile global loads EARLY (latency hides under ds_read+MFMA)
    short8 av[2], bv[2];
    if (have) {
#pragma unroll
      for (int p = 0; p < 2; ++p) {
        int r = srow + p * 64;
        av[p] = *(const short8*)&A[(size_t)(bm0 + r) * K + k0 + 32 + scol];
        int n = bn0 + r;
        bv[p] = (short8)0;
        if (n < N) bv[p] = *(const short8*)&W[(size_t)n * K + k0 + 32 + scol];
      }
    }
    short8 af[4], bfr[4];
#pragma unroll
    for (int i = 0; i < 4; i++) af[i] = *(const short8*)&sA[cur][(wm + i * 16 + lrow) * SA_STR + kh];
#pragma unroll
    for (int j = 0; j < 4; j++) bfr[j] = *(const short8*)&sB[cur][(wn + j * 16 + lrow) * SA_STR + kh];
#pragma unroll
    for (int i = 0; i < 4; i++)
#pragma unroll
      for (int j = 0; j < 4; j++)
        acc[i][j] = __builtin_amdgcn_mfma_f32_16x16x32_bf16(af[i], bfr[j], acc[i][j], 0, 0, 0);
    // write staged regs into the other buffer (vmcnt wait lands here, after MFMA)
    if (have) {
      int nxt = cur ^ 1;
#pragma unroll
      for (int p = 0; p < 2; ++p) {
        int r = srow + p * 64;
        *(short8*)&sA[nxt][r * SA_STR + scol] = av[p];
        *(short8*)&sB[nxt][r * SA_STR + scol] = bv[p];
      }
    }
    __syncthreads();
    cur ^= 1;
  }

  int orow4 = (lane >> 4) * 4;
  int ocol = lane & 15;
#pragma unroll
  for (int i = 0; i < 4; i++)
#pragma unroll
    for (int j = 0; j < 4; j++)
#pragma unroll
      for (int r = 0; r < 4; r++) {
        int row = bm0 + wm + i * 16 + orow4 + r;
        int col = bn0 + wn + j * 16 + ocol;
        if (col >= N) continue;
        float v = acc[i][j][r];
        size_t idx = (size_t)row * N + col;
        if (EPI == 0) {
          ((short*)outp)[idx] = f2bf(v);
        } else if (EPI == 1) {
          ((short*)outp)[idx] = f2bf(v + bias[col]);
        } else if (EPI == 2) {
          ((short*)outp)[idx] = f2bf(silu_f(v + bias[col]));
        } else if (EPI == 3) {
          ((short*)outp)[idx] = f2bf(softplus_f(v + bias[col]));
        } else if (EPI == 4) {
          float t = silu_f(v + bias[col]) * bf2f(mul[idx]);
          ((short*)outp)[idx] = f2bf(t);
        } else if (EPI == 5) {
          ((float*)outp)[idx] = v;
        } else if (EPI == 6) {
          int b = b0 + (row >> 12);
          float t = v + bias[col];
          ((float*)outp)[idx] = xres[idx] + modp[b * 3072 + 2048 + col] * t;
        } else if (EPI == 7) {
          float t = silu_f(v) * bf2f(mul[idx]);
          ((short*)outp)[idx] = f2bf(t);
        }
      }
}

// ---------------- full-tile bf16 GEMM via global_load_lds ----------------
// 2-phase double-buffered (T3 minimum recipe) + bijective XCD swizzle (T1/m204).
// Requires M%128==0, N%128==0, K%32==0, grid count % 8 == 0.
// EPI: 0 = plain bf16 store, 7 = silu(v)*mul store.
template <int EPI>
__global__ __launch_bounds__(256) void gemm_lds_k(
    const short* __restrict__ A, const short* __restrict__ W,
    const short* mul, void* outp, int N, int K) {
  __shared__ short sA[2][128 * 32];
  __shared__ short sB[2][128 * 32];
  int tid = threadIdx.x;
  int wave = tid >> 6, lane = tid & 63;
  // XCD-aware bijective swizzle: contiguous tile chunk per XCD (nwg % 8 == 0)
  int nwg = gridDim.x * gridDim.y;
  int orig = blockIdx.y * gridDim.x + blockIdx.x;
  int cpx = nwg >> 3;
  int wg = (orig & 7) * cpx + (orig >> 3);
  int bm0 = (wg / gridDim.x) * 128;
  int bn0 = (wg % gridDim.x) * 128;
  int wm = (wave >> 1) * 64, wn = (wave & 1) * 64;
  int lrow = lane & 15, kh = (lane >> 4) * 8;
  int srow = tid >> 2;       // 0..63
  int scol = (tid & 3) * 8;  // shorts
  int soff = srow * 32 + scol;

  const short* Ab = A + (size_t)(bm0 + srow) * K + scol;
  const short* Bb = W + (size_t)(bn0 + srow) * K + scol;

  f32x4 acc[4][4];
#pragma unroll
  for (int i = 0; i < 4; i++)
#pragma unroll
    for (int j = 0; j < 4; j++) acc[i][j] = (f32x4)0.f;

  // prologue: stage k0=0 into buffer 0
  gld16(Ab, &sA[0][soff]);
  gld16(Ab + (size_t)64 * K, &sA[0][soff + 64 * 32]);
  gld16(Bb, &sB[0][soff]);
  gld16(Bb + (size_t)64 * K, &sB[0][soff + 64 * 32]);
  __syncthreads();

  int cur = 0;
  for (int k0 = 0; k0 < K; k0 += 32) {
    int nxt = cur ^ 1;
    if (k0 + 32 < K) {
      // issue next-tile prefetch first; its vmcnt(0) wait lands at the
      // end-of-iteration barrier, overlapping ds_read + MFMA below
      gld16(Ab + k0 + 32, &sA[nxt][soff]);
      gld16(Ab + k0 + 32 + (size_t)64 * K, &sA[nxt][soff + 64 * 32]);
      gld16(Bb + k0 + 32, &sB[nxt][soff]);
      gld16(Bb + k0 + 32 + (size_t)64 * K, &sB[nxt][soff + 64 * 32]);
    }
    short8 af[4], bfr[4];
#pragma unroll
    for (int i = 0; i < 4; i++) af[i] = *(const short8*)&sA[cur][(wm + i * 16 + lrow) * 32 + kh];
#pragma unroll
    for (int j = 0; j < 4; j++) bfr[j] = *(const short8*)&sB[cur][(wn + j * 16 + lrow) * 32 + kh];
#pragma unroll
    for (int i = 0; i < 4; i++)
#pragma unroll
      for (int j = 0; j < 4; j++)
        acc[i][j] = __builtin_amdgcn_mfma_f32_16x16x32_bf16(af[i], bfr[j], acc[i][j], 0, 0, 0);
    __syncthreads();  // single vmcnt(0)+lgkmcnt(0)+barrier per K-step
    cur = nxt;
  }

  int orow4 = (lane >> 4) * 4;
  int ocol = lane & 15;
#pragma unroll
  for (int i = 0; i < 4; i++)
#pragma unroll
    for (int j = 0; j < 4; j++)
#pragma unroll
      for (int r = 0; r < 4; r++) {
        int row = bm0 + wm + i * 16 + orow4 + r;
        int col = bn0 + wn + j * 16 + ocol;
        float v = acc[i][j][r];
        size_t idx = (size_t)row * N + col;
        if (EPI == 0) {
          ((short*)outp)[idx] = f2bf(v);
        } else if (EPI == 7) {
          float t = silu_f(v) * bf2f(mul[idx]);
          ((short*)outp)[idx] = f2bf(t);
        }
      }
}

// ---------------- causal depthwise conv (DC=4) + SiLU ----------------
__global__ __launch_bounds__(256) void conv_kernel(const short* __restrict__ xm,
    const float* __restrict__ cw, const float* __restrict__ cb, short* __restrict__ xc) {
  size_t idx = (size_t)blockIdx.x * 256 + threadIdx.x;
  int d = (int)(idx & (DIn - 1));
  size_t bt = idx >> 11;
  int t = (int)(bt & (Ln - 1));
  f32x4 w = *(const f32x4*)(cw + d * 4);
  float wj[4] = {w.x, w.y, w.z, w.w};
  float acc = cb[d];
#pragma unroll
  for (int j = 0; j < 4; ++j) {
    int tt = t - 3 + j;
    if (tt >= 0) acc += bf2f(xm[(bt - 3 + j) * DIn + d]) * wj[j];
  }
  xc[idx] = f2bf(silu_f(acc));
}

// ---------------- slice dbl[:, :64] -> bf16 ----------------
__global__ __launch_bounds__(256) void dtslice_kernel(const float* __restrict__ dbl,
                                                      short* __restrict__ dtb) {
  int idx = blockIdx.x * 256 + threadIdx.x;
  int row = idx >> 6, col = idx & 63;
  dtb[idx] = f2bf(dbl[(size_t)row * 96 + col]);
}

// ================= chunked parallel selective scan =================
// thread g -> d = g&2047, c = (g>>11)&63, b = g>>17 (within chunk-batch BC)
// pass 1: local scan from h=0 over CLn steps; store h_end[16] + sum(dt)
__global__ __launch_bounds__(256) void scan_part1(const short* __restrict__ dt,
    const short* __restrict__ xc, const float* __restrict__ dbl,
    const float* __restrict__ A_log, float* __restrict__ hq, float* __restrict__ sd) {
  __shared__ float sB[CLn * 16];
  int tid = threadIdx.x;
  int g = blockIdx.x * 256 + tid;
  int d = g & (DIn - 1);
  int r = g >> 11;
  int c = r & (NCH - 1);
  int b = r >> 6;
  size_t rb = (size_t)b * Ln + (size_t)c * CLn;
  // stage B rows (shared by whole block): 64 rows x 16 floats = 4 KB
  {
    int row = tid >> 2, q = tid & 3;
    *(f32x4*)&sB[row * 16 + q * 4] = *(const f32x4*)(dbl + (rb + row) * 96 + 64 + q * 4);
  }
  __syncthreads();
  float A[16], h[16];
#pragma unroll
  for (int s = 0; s < 16; ++s) {
    A[s] = -__expf(A_log[d * 16 + s]);
    h[s] = 0.f;
  }
  // structure check: A[s] == (s+1)*A[0] (Mamba arange init) -> one exp + powers
  bool st = true;
#pragma unroll
  for (int s = 1; s < 16; ++s)
    st = st && (fabsf(A[s] - (float)(s + 1) * A[0]) <= 1e-4f * fabsf(A[s]));
  float A0 = A[0];
  float sum = 0.f;
  const short* dp = dt + rb * DIn + d;
  const short* xp = xc + rb * DIn + d;
  short dtn = *dp, xcn = *xp;
  if (st) {
    for (int t = 0; t < CLn; ++t) {
      float dtv = bf2f(dtn), xv = bf2f(xcn);
      int tn = (t + 1 < CLn) ? t + 1 : t;
      dtn = dp[(size_t)tn * DIn];
      xcn = xp[(size_t)tn * DIn];
      float u = dtv * xv;
      sum += dtv;
      const f32x4* bp = (const f32x4*)&sB[t * 16];
      f32x4 b0 = bp[0], b1 = bp[1], b2 = bp[2], b3 = bp[3];
      float bv[16] = {b0.x, b0.y, b0.z, b0.w, b1.x, b1.y, b1.z, b1.w,
                      b2.x, b2.y, b2.z, b2.w, b3.x, b3.y, b3.z, b3.w};
      float qe = __expf(dtv * A0);
      float pk = qe;
#pragma unroll
      for (int s = 0; s < 16; ++s) {
        h[s] = h[s] * pk + u * bv[s];
        pk *= qe;
      }
    }
  } else {
    for (int t = 0; t < CLn; ++t) {
      float dtv = bf2f(dtn), xv = bf2f(xcn);
      int tn = (t + 1 < CLn) ? t + 1 : t;
      dtn = dp[(size_t)tn * DIn];
      xcn = xp[(size_t)tn * DIn];
      float u = dtv * xv;
      sum += dtv;
      const f32x4* bp = (const f32x4*)&sB[t * 16];
      f32x4 b0 = bp[0], b1 = bp[1], b2 = bp[2], b3 = bp[3];
      float bv[16] = {b0.x, b0.y, b0.z, b0.w, b1.x, b1.y, b1.z, b1.w,
                      b2.x, b2.y, b2.z, b2.w, b3.x, b3.y, b3.z, b3.w};
#pragma unroll
      for (int s = 0; s < 16; ++s) h[s] = h[s] * __expf(dtv * A[s]) + u * bv[s];
    }
  }
  size_t bd = (size_t)b * DIn + d;
  f32x4* out = (f32x4*)(hq + (bd * NCH + c) * 16);
#pragma unroll
  for (int i = 0; i < 4; ++i) {
    f32x4 o; o.x = h[4 * i]; o.y = h[4 * i + 1]; o.z = h[4 * i + 2]; o.w = h[4 * i + 3];
    out[i] = o;
  }
  sd[bd * NCH + c] = sum;
}

// pass combine: thread per (b,d,s); sequential over chunks; hq becomes h_start
__global__ __launch_bounds__(256) void scan_combine(const float* __restrict__ A_log,
    const float* __restrict__ sd, float* hq) {
  int g = blockIdx.x * 256 + threadIdx.x;
  int s = g & 15;
  size_t bd = (size_t)(g >> 4);
  int d = (int)(bd & (DIn - 1));
  float A = -__expf(A_log[d * 16 + s]);
  float H = 0.f;
  for (int c = 0; c < NCH; ++c) {
    size_t idx = (bd * NCH + c) * 16 + s;
    float he = hq[idx];
    float e = __expf(A * sd[bd * NCH + c]);
    hq[idx] = H;
    H = H * e + he;
  }
}

// pass 2: local scan seeded with h_start; y = h·C + xc*D. dt/y may alias (read-t-then-write-t).
__global__ __launch_bounds__(256) void scan_part2(const short* dt,
    const short* __restrict__ xc, const float* __restrict__ dbl,
    const float* __restrict__ A_log, const float* __restrict__ Dv,
    const float* __restrict__ hq, short* y) {
  __shared__ float sBC[CLn * 32];
  int tid = threadIdx.x;
  int g = blockIdx.x * 256 + tid;
  int d = g & (DIn - 1);
  int r = g >> 11;
  int c = r & (NCH - 1);
  int b = r >> 6;
  size_t rb = (size_t)b * Ln + (size_t)c * CLn;
  // stage B+C rows (shared by whole block): 64 rows x 32 floats = 8 KB
  {
    int row = tid >> 2, q = tid & 3;
    const float* src = dbl + (rb + row) * 96 + 64 + q * 8;
    *(f32x4*)&sBC[row * 32 + q * 8] = *(const f32x4*)src;
    *(f32x4*)&sBC[row * 32 + q * 8 + 4] = *(const f32x4*)(src + 4);
  }
  __syncthreads();
  size_t bd = (size_t)b * DIn + d;
  float A[16], h[16];
#pragma unroll
  for (int s = 0; s < 16; ++s) A[s] = -__expf(A_log[d * 16 + s]);
  const f32x4* hin = (const f32x4*)(hq + (bd * NCH + c) * 16);
#pragma unroll
  for (int i = 0; i < 4; ++i) {
    f32x4 qv = hin[i];
    h[4 * i] = qv.x; h[4 * i + 1] = qv.y; h[4 * i + 2] = qv.z; h[4 * i + 3] = qv.w;
  }
  bool st = true;
#pragma unroll
  for (int s = 1; s < 16; ++s)
    st = st && (fabsf(A[s] - (float)(s + 1) * A[0]) <= 1e-4f * fabsf(A[s]));
  float A0 = A[0];
  float Dd = Dv[d];
  const short* dp = dt + rb * DIn + d;
  const short* xp = xc + rb * DIn + d;
  short* yp = y + rb * DIn + d;
  short dtn = *dp, xcn = *xp;
  if (st) {
    for (int t = 0; t < CLn; ++t) {
      float dtv = bf2f(dtn), xv = bf2f(xcn);
      int tn = (t + 1 < CLn) ? t + 1 : t;
      dtn = dp[(size_t)tn * DIn];   // prefetch before y-store (alias-safe: different row)
      xcn = xp[(size_t)tn * DIn];
      float u = dtv * xv;
      const f32x4* pp = (const f32x4*)&sBC[t * 32];
      f32x4 v0 = pp[0], v1 = pp[1], v2 = pp[2], v3 = pp[3];
      f32x4 v4 = pp[4], v5 = pp[5], v6 = pp[6], v7 = pp[7];
      float bc[32] = {v0.x, v0.y, v0.z, v0.w, v1.x, v1.y, v1.z, v1.w,
                      v2.x, v2.y, v2.z, v2.w, v3.x, v3.y, v3.z, v3.w,
                      v4.x, v4.y, v4.z, v4.w, v5.x, v5.y, v5.z, v5.w,
                      v6.x, v6.y, v6.z, v6.w, v7.x, v7.y, v7.z, v7.w};
      float qe = __expf(dtv * A0);
      float pk = qe, acc = 0.f;
#pragma unroll
      for (int s = 0; s < 16; ++s) {
        h[s] = h[s] * pk + u * bc[s];
        acc += h[s] * bc[16 + s];
        pk *= qe;
      }
      yp[(size_t)t * DIn] = f2bf(acc + xv * Dd);
    }
  } else {
    for (int t = 0; t < CLn; ++t) {
      float dtv = bf2f(dtn), xv = bf2f(xcn);
      int tn = (t + 1 < CLn) ? t + 1 : t;
      dtn = dp[(size_t)tn * DIn];
      xcn = xp[(size_t)tn * DIn];
      float u = dtv * xv;
      const f32x4* pp = (const f32x4*)&sBC[t * 32];
      f32x4 v0 = pp[0], v1 = pp[1], v2 = pp[2], v3 = pp[3];
      f32x4 v4 = pp[4], v5 = pp[5], v6 = pp[6], v7 = pp[7];
      float bc[32] = {v0.x, v0.y, v0.z, v0.w, v1.x, v1.y, v1.z, v1.w,
                      v2.x, v2.y, v2.z, v2.w, v3.x, v3.y, v3.z, v3.w,
                      v4.x, v4.y, v4.z, v4.w, v5.x, v5.y, v5.z, v5.w,
                      v6.x, v6.y, v6.z, v6.w, v7.x, v7.y, v7.z, v7.w};
      float acc = 0.f;
#pragma unroll
      for (int s = 0; s < 16; ++s) {
        h[s] = h[s] * __expf(dtv * A[s]) + u * bc[s];
        acc += h[s] * bc[16 + s];
      }
      yp[(size_t)t * DIn] = f2bf(acc + xv * Dd);
    }
  }
}

extern "C" void kernel_launch(void* const* d_in, const int* in_sizes, int n_in,
                              void* d_out, int out_size, void* d_ws, size_t ws_size,
                              hipStream_t stream) {
  const float* x = (const float*)d_in[0];
  const float* c = (const float*)d_in[1];
  const float* adaln_w = (const float*)d_in[2];
  const float* adaln_b = (const float*)d_in[3];
  const float* hgd_w1 = (const float*)d_in[4];
  const float* hgd_b1 = (const float*)d_in[5];
  const float* hgd_w2 = (const float*)d_in[6];
  const float* hgd_b2 = (const float*)d_in[7];
  const float* hgf_wm = (const float*)d_in[8];
  const float* hgf_bm = (const float*)d_in[9];
  const float* hgf_wr = (const float*)d_in[10];
  const float* hgf_br = (const float*)d_in[11];
  const float* hgf_wf = (const float*)d_in[12];
  const float* hgf_bf = (const float*)d_in[13];
  const float* in_w = (const float*)d_in[14];
  const float* conv_w = (const float*)d_in[15];
  const float* conv_b = (const float*)d_in[16];
  const float* xproj_w = (const float*)d_in[17];
  const float* dtproj_w = (const float*)d_in[18];
  const float* dt_bias = (const float*)d_in[19];
  const float* A_log = (const float*)d_in[20];
  const float* Dv = (const float*)d_in[21];
  const float* out_w = (const float*)d_in[22];
  (void)in_sizes; (void)n_in; (void)out_size;

  // ---- persistent region: bf16 weights + modulation ----
  char* ws = (char*)d_ws;
  size_t off = 0;
  auto alloc = [&](size_t bytes) -> void* {
    void* p = ws + off;
    off += (bytes + 255) & ~(size_t)255;
    return p;
  };
  short* w1b = (short*)alloc((size_t)256 * 1024 * 2);
  short* w2b = (short*)alloc((size_t)1024 * 256 * 2);
  short* wmb = (short*)alloc((size_t)256 * 1024 * 2);
  short* wrb = (short*)alloc((size_t)256 * 1024 * 2);
  short* wfb = (short*)alloc((size_t)1024 * 256 * 2);
  short* inwb = (short*)alloc((size_t)4096 * 1024 * 2);
  short* xpb = (short*)alloc((size_t)96 * 2048 * 2);
  short* dtpb = (short*)alloc((size_t)2048 * 64 * 2);
  short* owb = (short*)alloc((size_t)1024 * 2048 * 2);
  float* modb = (float*)alloc((size_t)Bn * 3072 * 4);
  size_t persist = off;

  // ---- batch-chunking: per-chunk bytes = Mc*14976 (incl. hq/sd) ----
  int BC = 8;
  while (BC > 1 && persist + (size_t)BC * Ln * 14976 > ws_size) BC >>= 1;
  int nchunk = 8 / BC;
  size_t Mc = (size_t)BC * Ln;

  short* x1 = (short*)alloc(Mc * 1024 * 2);
  short* hd = (short*)alloc(Mc * 1024 * 2);
  short* xm = (short*)alloc(Mc * 2048 * 2);   // in_proj x -> dt -> y_raw -> y
  short* xct = (short*)alloc(Mc * 2048 * 2);  // conv out; t1 aliases
  float* dbl = (float*)alloc(Mc * 96 * 4);
  short* dtb = (short*)alloc(Mc * 64 * 2);
  float* hq = (float*)alloc((size_t)BC * DIn * NCH * 16 * 4);
  float* sd = (float*)alloc((size_t)BC * DIn * NCH * 4);
  short* t1 = xct;

  auto conv1 = [&](const float* src, short* dst, int n) {
    f2bf4_kernel<<<(n / 4 + 255) / 256, 256, 0, stream>>>(src, dst, n / 4);
  };
  conv1(hgd_w1, w1b, 256 * 1024);
  conv1(hgd_w2, w2b, 1024 * 256);
  conv1(hgf_wm, wmb, 256 * 1024);
  conv1(hgf_wr, wrb, 256 * 1024);
  conv1(hgf_wf, wfb, 1024 * 256);
  conv1(in_w, inwb, 4096 * 1024);
  conv1(xproj_w, xpb, 96 * 2048);
  conv1(dtproj_w, dtpb, 2048 * 64);
  conv1(out_w, owb, 1024 * 2048);

  modcalc_kernel<<<(Bn * 3072) / 4, 256, 0, stream>>>(c, adaln_w, adaln_b, modb);

  dim3 blk(256);
  int gy = (int)(Mc / 128);
  for (int ck = 0; ck < nchunk; ++ck) {
    int b0 = ck * BC;
    const float* xch = x + (size_t)b0 * Ln * Hn;
    float* och = (float*)d_out + (size_t)b0 * Ln * Hn;

    ln_mod_kernel<<<(int)(Mc / 4), blk, 0, stream>>>(xch, modb, x1, b0);
    gemm_k<2><<<dim3(2, gy), blk, 0, stream>>>(x1, w1b, hgd_b1, nullptr, nullptr, nullptr, t1, 256, 1024, 0);
    gemm_k<1><<<dim3(8, gy), blk, 0, stream>>>(t1, w2b, hgd_b2, nullptr, nullptr, nullptr, hd, 1024, 256, 0);
    gemm_lds_k<0><<<dim3(16, gy), blk, 0, stream>>>(hd, inwb, nullptr, xm, 2048, 1024);
    conv_kernel<<<(int)(Mc * 2048 / 256), blk, 0, stream>>>(xm, conv_w, conv_b, xct);
    gemm_k<5><<<dim3(1, gy), blk, 0, stream>>>(xct, xpb, nullptr, nullptr, nullptr, nullptr, dbl, 96, 2048, 0);
    dtslice_kernel<<<(int)(Mc * 64 / 256), blk, 0, stream>>>(dbl, dtb);
    gemm_k<3><<<dim3(16, gy), blk, 0, stream>>>(dtb, dtpb, dt_bias, nullptr, nullptr, nullptr, xm, 2048, 64, 0);
    // chunked parallel scan: dt(xm), xc(xct), B/C(dbl) -> y_raw in place in xm
    scan_part1<<<(int)(BC * 512), blk, 0, stream>>>(xm, xct, dbl, A_log, hq, sd);
    scan_combine<<<(int)(BC * 128), blk, 0, stream>>>(A_log, sd, hq);
    scan_part2<<<(int)(BC * 512), blk, 0, stream>>>(xm, xct, dbl, A_log, Dv, hq, xm);
    // gating: y = silu(hd @ Wz^T) * y_raw (in place)
    gemm_lds_k<7><<<dim3(16, gy), blk, 0, stream>>>(hd, inwb + (size_t)2048 * 1024, xm, xm, 2048, 1024);
    gemm_lds_k<0><<<dim3(8, gy), blk, 0, stream>>>(xm, owb, nullptr, hd, 1024, 2048);
    gemm_k<2><<<dim3(2, gy), blk, 0, stream>>>(hd, wmb, hgf_bm, nullptr, nullptr, nullptr, t1, 256, 1024, 0);
    gemm_k<4><<<dim3(2, gy), blk, 0, stream>>>(x1, wrb, hgf_br, t1, nullptr, nullptr, t1, 256, 1024, 0);
    gemm_k<6><<<dim3(8, gy), blk, 0, stream>>>(t1, wfb, hgf_bf, nullptr, xch, modb, och, 1024, 256, b0);
  }
}